// Round 4
// baseline (119.812 us; speedup 1.0000x reference)
//
#include <hip/hip_runtime.h>

// SmallSMBlock: K = Conv2d(1,9,3,'same')(image)+b per pixel; y[b] = 9-tap apply to x[b].
// Memory-bound: ideal traffic ~68 MB (image 4 + x 32 + y 32) -> ~11 us floor.
// R4 = RETRY of R3 measurement round (R3 died to container infra, not the kernel):
// identical kernel launched TWICE; dur_us(R4) - dur_us(R2) = true kernel cost,
// since rocprof top-5 is saturated by the harness's 42-us/268-MB poison fills
// and the kernel never appears in it.

#define H  1024
#define W  1024
#define NB 8
#define TD 32            // tile dim (pixels)
#define TP 34            // padded tile dim
#define LS 36            // LDS row stride (floats): keeps 4*cg reads 16B-aligned
#define LT (TP * LS)     // floats per staged tile (34*36 = 1224)

__global__ __launch_bounds__(256)
void smblock_kernel(const float* __restrict__ image,
                    const float* __restrict__ x,
                    const float* __restrict__ kw,   // (9,1,3,3)
                    const float* __restrict__ kb,   // (9,)
                    float* __restrict__ y)          // (8,1,H,W)
{
    __shared__ float simg[LT];
    __shared__ float sx[2][LT];

    const int h0  = blockIdx.y * TD;
    const int w0  = blockIdx.x * TD;
    const int tid = threadIdx.x;
    const int r   = tid >> 3;      // pixel row 0..31
    const int cg  = tid & 7;       // col group: pixel cols 4cg..4cg+3

    const size_t gint = (size_t)(h0 + r) * W + (w0 + 4 * cg);
    const int    lint = (r + 1) * LS + (4 * cg + 1);

    // halo: 132 border elements of the 34x34 padded tile
    int hr = -1, hc = -1;
    {
        const int wv = tid >> 6, ln = tid & 63;
        if      (wv == 0) { if (ln < TP) { hr = 0;      hc = ln;     } }
        else if (wv == 1) { if (ln < TP) { hr = TP - 1; hc = ln;     } }
        else if (wv == 2) { if (ln < TD) { hr = ln + 1; hc = 0;      } }
        else              { if (ln < TD) { hr = ln + 1; hc = TP - 1; } }
    }
    const bool has_halo = (hr >= 0);
    const int  gh = h0 + hr - 1, gw = w0 + hc - 1;
    const bool hin = has_halo && ((unsigned)gh < H) && ((unsigned)gw < W);
    const size_t ghalo = (size_t)gh * W + gw;
    const int    lhalo = hr * LS + hc;

    // ---- stage image + batch-0 x ----
    {
        float4 iv = *(const float4*)(image + gint);
        float4 xv = *(const float4*)(x + gint);
        float ihv = hin ? image[ghalo] : 0.f;
        float xhv = hin ? x[ghalo]     : 0.f;
        simg[lint]  = iv.x; simg[lint+1]  = iv.y; simg[lint+2]  = iv.z; simg[lint+3]  = iv.w;
        sx[0][lint] = xv.x; sx[0][lint+1] = xv.y; sx[0][lint+2] = xv.z; sx[0][lint+3] = xv.w;
        if (has_halo) { simg[lhalo] = ihv; sx[0][lhalo] = xhv; }
    }
    __syncthreads();

    // ---- per-pixel predicted kernels: K[j][t] for pixels (r, 4cg+j) ----
    float K[4][9];
    #pragma unroll
    for (int j = 0; j < 4; ++j)
        #pragma unroll
        for (int t = 0; t < 9; ++t) K[j][t] = kb[t];

    #pragma unroll
    for (int a = 0; a < 3; ++a) {
        const float* row = &simg[(r + a) * LS + 4 * cg];
        float4 f4 = *(const float4*)row;
        float2 f2 = *(const float2*)(row + 4);
        float wv[6] = { f4.x, f4.y, f4.z, f4.w, f2.x, f2.y };
        #pragma unroll
        for (int d = 0; d < 3; ++d)
            #pragma unroll
            for (int t = 0; t < 9; ++t) {
                float wgt = kw[t * 9 + 3 * a + d];   // wave-uniform -> s_load
                #pragma unroll
                for (int j = 0; j < 4; ++j)
                    K[j][t] += wgt * wv[j + d];
            }
    }

    // ---- apply per batch; double-buffered x, one sync per batch ----
    #pragma unroll
    for (int b = 0; b < NB; ++b) {
        float4 pv; float phv = 0.f;
        if (b + 1 < NB) {
            const float* xn = x + (size_t)(b + 1) * ((size_t)H * W);
            pv  = *(const float4*)(xn + gint);
            if (hin) phv = xn[ghalo];
        }

        const float* sb = sx[b & 1];
        float a0 = 0.f, a1 = 0.f, a2 = 0.f, a3 = 0.f;
        #pragma unroll
        for (int a = 0; a < 3; ++a) {
            const float* row = &sb[(r + a) * LS + 4 * cg];
            float4 f4 = *(const float4*)row;    // ds_read_b128
            float2 f2 = *(const float2*)(row + 4);
            float wv[6] = { f4.x, f4.y, f4.z, f4.w, f2.x, f2.y };
            #pragma unroll
            for (int d = 0; d < 3; ++d) {
                a0 += wv[0 + d] * K[0][3 * a + d];
                a1 += wv[1 + d] * K[1][3 * a + d];
                a2 += wv[2 + d] * K[2][3 * a + d];
                a3 += wv[3 + d] * K[3][3 * a + d];
            }
        }
        float4 o; o.x = a0; o.y = a1; o.z = a2; o.w = a3;
        *(float4*)(y + (size_t)b * ((size_t)H * W) + gint) = o;

        if (b + 1 < NB) {
            float* dst = sx[(b + 1) & 1];
            dst[lint]   = pv.x; dst[lint+1] = pv.y;
            dst[lint+2] = pv.z; dst[lint+3] = pv.w;
            if (has_halo) dst[lhalo] = phv;
            __syncthreads();
        }
    }
}

extern "C" void kernel_launch(void* const* d_in, const int* in_sizes, int n_in,
                              void* d_out, int out_size, void* d_ws, size_t ws_size,
                              hipStream_t stream)
{
    const float* image = (const float*)d_in[0];  // (1,1024,1024)
    const float* x     = (const float*)d_in[1];  // (8,1,1024,1024)
    const float* kw    = (const float*)d_in[2];  // (9,1,3,3)
    const float* kb    = (const float*)d_in[3];  // (9,)
    float* y = (float*)d_out;                    // (8,1,1024,1024)

    dim3 grid(W / TD, H / TD);
    // MEASUREMENT: two identical, idempotent launches. dur_us(R4)-dur_us(R2)
    // = true kernel cost (rocprof top-5 is masked by harness poison fills).
    smblock_kernel<<<grid, 256, 0, stream>>>(image, x, kw, kb, y);
    smblock_kernel<<<grid, 256, 0, stream>>>(image, x, kw, kb, y);
}

// Round 6
// 102.600 us; speedup vs baseline: 1.1678x; 1.1678x over previous
//
#include <hip/hip_runtime.h>

// SmallSMBlock: K = Conv2d(1,9,3,'same')(image)+b per pixel; y[b] = 9-tap apply to x[b].
// Compulsory traffic ~68 MB (image 4 + x 32 + y 32) -> ~10.8 us floor at 6.3 TB/s.
// Measured R2 kernel (LDS + 8 barriers): 18.9 us (= dur_us(R4 double) - dur_us(R2 single)).
// R6 = RETRY of R5 (broker timeout, kernel never ran): barrier-free. Each thread
// reads its 3x6 stencil window straight from global (overlap served by L1/L2; tile
// working set ~5 KB/batch/block << 32 KB L1), clamped row addresses + multiplicative
// border masks (branchless), depth-1 register prefetch of the next batch.
// No LDS, no __syncthreads -> waves stream desynchronized.

#define H  1024
#define W  1024
#define NB 8
#define HW ((size_t)H * (size_t)W)

__global__ __launch_bounds__(256)
void smblock_kernel(const float* __restrict__ image,
                    const float* __restrict__ x,
                    const float* __restrict__ kw,   // (9,1,3,3)
                    const float* __restrict__ kb,   // (9,)
                    float* __restrict__ y)          // (8,1,H,W)
{
    const int tid = threadIdx.x;
    const int r   = tid >> 3;                    // pixel row in 32x32 tile
    const int cg  = tid & 7;                     // col group (4 adjacent cols)
    const int h   = (int)blockIdx.y * 32 + r;
    const int w   = (int)blockIdx.x * 32 + 4 * cg;

    // ---- per-row 32-bit offsets (row-clamped, always in-bounds) + validity masks ----
    unsigned o4[3], ol[3], orr[3];
    float mc[3], mlm[3], mrm[3];
    {
        const bool lv = (w >= 1);
        const bool rv = (w + 4 < W);
        #pragma unroll
        for (int a = 0; a < 3; ++a) {
            int hh = h + a - 1;
            int hc = hh < 0 ? 0 : (hh > H - 1 ? H - 1 : hh);
            unsigned ro = (unsigned)hc * W;
            o4[a]  = ro + w;
            ol[a]  = ro + (lv ? (w - 1) : w);
            orr[a] = ro + (rv ? (w + 4) : w);
            float hv = ((unsigned)hh < (unsigned)H) ? 1.f : 0.f;
            mc[a]  = hv;
            mlm[a] = lv ? hv : 0.f;
            mrm[a] = rv ? hv : 0.f;
        }
    }

    // ---- issue batch-0 x loads immediately (in flight during K compute) ----
    float nxt[18];
    #pragma unroll
    for (int a = 0; a < 3; ++a) {
        float4 f = *(const float4*)(x + o4[a]);
        nxt[6*a+0] = x[ol[a]];
        nxt[6*a+1] = f.x; nxt[6*a+2] = f.y; nxt[6*a+3] = f.z; nxt[6*a+4] = f.w;
        nxt[6*a+5] = x[orr[a]];
    }

    // ---- per-pixel predicted kernels K[j][t] for pixels (h, w+j) ----
    float K[4][9];
    #pragma unroll
    for (int t = 0; t < 9; ++t) {
        float bt = kb[t];                        // uniform -> s_load
        #pragma unroll
        for (int j = 0; j < 4; ++j) K[j][t] = bt;
    }
    #pragma unroll
    for (int a = 0; a < 3; ++a) {
        float4 f = *(const float4*)(image + o4[a]);
        float vl = image[ol[a]] * mlm[a];
        float vr = image[orr[a]] * mrm[a];
        float v[6] = { vl, f.x*mc[a], f.y*mc[a], f.z*mc[a], f.w*mc[a], vr };
        #pragma unroll
        for (int d = 0; d < 3; ++d)
            #pragma unroll
            for (int t = 0; t < 9; ++t) {
                float wgt = kw[t * 9 + 3 * a + d];   // uniform -> s_load
                #pragma unroll
                for (int j = 0; j < 4; ++j)
                    K[j][t] += wgt * v[j + d];
            }
    }

    // ---- batch loop: depth-1 register pipeline, zero barriers ----
    float cur[18];
    #pragma unroll 1
    for (int b = 0; b < NB; ++b) {
        // commit prefetched values with border masks (clamped reads are real data)
        #pragma unroll
        for (int a = 0; a < 3; ++a) {
            cur[6*a+0] = nxt[6*a+0] * mlm[a];
            cur[6*a+1] = nxt[6*a+1] * mc[a];
            cur[6*a+2] = nxt[6*a+2] * mc[a];
            cur[6*a+3] = nxt[6*a+3] * mc[a];
            cur[6*a+4] = nxt[6*a+4] * mc[a];
            cur[6*a+5] = nxt[6*a+5] * mrm[a];
        }
        // prefetch next batch (uniform SGPR base + 32-bit lane offsets)
        if (b + 1 < NB) {
            const float* xb = x + (size_t)(b + 1) * HW;
            #pragma unroll
            for (int a = 0; a < 3; ++a) {
                float4 f = *(const float4*)(xb + o4[a]);
                nxt[6*a+0] = xb[ol[a]];
                nxt[6*a+1] = f.x; nxt[6*a+2] = f.y; nxt[6*a+3] = f.z; nxt[6*a+4] = f.w;
                nxt[6*a+5] = xb[orr[a]];
            }
        }
        // y[b, h, w+j] = sum_{a,d} x[h+a-1, w+j+d-1] * K[j][3a+d]
        float a0 = 0.f, a1 = 0.f, a2 = 0.f, a3 = 0.f;
        #pragma unroll
        for (int a = 0; a < 3; ++a)
            #pragma unroll
            for (int d = 0; d < 3; ++d) {
                a0 += cur[6*a + 0 + d] * K[0][3*a+d];
                a1 += cur[6*a + 1 + d] * K[1][3*a+d];
                a2 += cur[6*a + 2 + d] * K[2][3*a+d];
                a3 += cur[6*a + 3 + d] * K[3][3*a+d];
            }
        float4 o; o.x = a0; o.y = a1; o.z = a2; o.w = a3;
        *(float4*)(y + (size_t)b * HW + (size_t)((unsigned)h * W + w)) = o;
    }
}

extern "C" void kernel_launch(void* const* d_in, const int* in_sizes, int n_in,
                              void* d_out, int out_size, void* d_ws, size_t ws_size,
                              hipStream_t stream)
{
    const float* image = (const float*)d_in[0];  // (1,1024,1024)
    const float* x     = (const float*)d_in[1];  // (8,1,1024,1024)
    const float* kw    = (const float*)d_in[2];  // (9,1,3,3)
    const float* kb    = (const float*)d_in[3];  // (9,)
    float* y = (float*)d_out;                    // (8,1,1024,1024)

    dim3 grid(W / 32, H / 32);
    smblock_kernel<<<grid, 256, 0, stream>>>(image, x, kw, kb, y);
}

// Round 7
// 102.412 us; speedup vs baseline: 1.1699x; 1.0018x over previous
//
#include <hip/hip_runtime.h>

// SmallSMBlock: K = Conv2d(1,9,3,'same')(image)+b per pixel; y[b] = 9-tap apply to x[b].
// Compulsory traffic ~68 MB -> ~10.8 us floor at 6.3 TB/s. Measured: R2 (LDS+barriers)
// and R6 (barrier-free, 32x32 tiles) both ~19 us => limiter is access geometry, not sync.
// R7: tile 512x8, 1024-thread blocks. A wave covers 256 contiguous cols -> every
// dwordx4 is a 1KB contiguous burst; blocks own 2KB-aligned page halves (DRAM page
// locality). x zero-padding folded into K once -> batch loop has no mask ops.
// Trade: row halo 25% of x reads (36->40 MB fetch).

#define H  1024
#define W  1024
#define NB 8
#define HW ((size_t)H * (size_t)W)

__global__ __launch_bounds__(1024)
void smblock_kernel(const float* __restrict__ image,
                    const float* __restrict__ x,
                    const float* __restrict__ kw,   // (9,1,3,3)
                    const float* __restrict__ kb,   // (9,)
                    float* __restrict__ y)          // (8,1,H,W)
{
    const int tid = threadIdx.x;
    const int tc  = tid & 127;                  // 128 col-groups * 4 cols = 512
    const int tr  = tid >> 7;                   // 8 rows per block
    const int h   = (int)blockIdx.y * 8  + tr;
    const int w   = (int)blockIdx.x * 512 + 4 * tc;

    // ---- row-clamped 32-bit offsets (always addressable) + border masks ----
    unsigned o4[3], ol[3], orr[3];
    float mrow[3];
    const float mleft  = (w >= 1)     ? 1.f : 0.f;   // tap w-1 valid?
    const float mright = (w + 4 < W)  ? 1.f : 0.f;   // tap w+4 valid?
    #pragma unroll
    for (int a = 0; a < 3; ++a) {
        int hh = h + a - 1;
        int hc = hh < 0 ? 0 : (hh > H - 1 ? H - 1 : hh);
        unsigned ro = (unsigned)hc * W;
        o4[a]  = ro + w;
        ol[a]  = ro + ((w >= 1)    ? (w - 1) : w);
        orr[a] = ro + ((w + 4 < W) ? (w + 4) : w);
        mrow[a] = ((unsigned)hh < (unsigned)H) ? 1.f : 0.f;
    }

    // ---- issue batch-0 x loads immediately (in flight during K compute) ----
    float nxt[18];
    #pragma unroll
    for (int a = 0; a < 3; ++a) {
        float4 f = *(const float4*)(x + o4[a]);
        nxt[6*a+0] = x[ol[a]];
        nxt[6*a+1] = f.x; nxt[6*a+2] = f.y; nxt[6*a+3] = f.z; nxt[6*a+4] = f.w;
        nxt[6*a+5] = x[orr[a]];
    }

    // ---- per-pixel predicted kernels K[j][t], image zero-padding via masks ----
    float K[4][9];
    #pragma unroll
    for (int t = 0; t < 9; ++t) {
        float bt = kb[t];                        // uniform -> s_load
        #pragma unroll
        for (int j = 0; j < 4; ++j) K[j][t] = bt;
    }
    #pragma unroll
    for (int a = 0; a < 3; ++a) {
        float4 f = *(const float4*)(image + o4[a]);
        float v[6] = { image[ol[a]] * (mleft * mrow[a]),
                       f.x * mrow[a], f.y * mrow[a], f.z * mrow[a], f.w * mrow[a],
                       image[orr[a]] * (mright * mrow[a]) };
        #pragma unroll
        for (int d = 0; d < 3; ++d)
            #pragma unroll
            for (int t = 0; t < 9; ++t) {
                float wgt = kw[t * 9 + 3 * a + d];   // uniform -> s_load
                #pragma unroll
                for (int j = 0; j < 4; ++j)
                    K[j][t] += wgt * v[j + d];
            }
    }

    // ---- fold x's zero-padding into K: zero taps that fall outside the image ----
    // tap (a,d) for pixel col w+j reads x[h+a-1, w+j+d-1]:
    //   row invalid -> mrow[a]; col < 0 only at (j=0,d=0,w=0); col > W-1 only at
    //   (j=3,d=2,w=W-4). After this, the batch loop needs NO masking at all.
    #pragma unroll
    for (int a = 0; a < 3; ++a) {
        #pragma unroll
        for (int d = 0; d < 3; ++d)
            #pragma unroll
            for (int j = 0; j < 4; ++j)
                K[j][3*a+d] *= mrow[a];
        K[0][3*a+0] *= mleft;
        K[3][3*a+2] *= mright;
    }

    // ---- batch loop: depth-1 register pipeline, zero barriers, zero masks ----
    float cur[18];
    #pragma unroll 1
    for (int b = 0; b < NB; ++b) {
        #pragma unroll
        for (int i = 0; i < 18; ++i) cur[i] = nxt[i];

        if (b + 1 < NB) {
            const float* xb = x + (size_t)(b + 1) * HW;
            #pragma unroll
            for (int a = 0; a < 3; ++a) {
                float4 f = *(const float4*)(xb + o4[a]);
                nxt[6*a+0] = xb[ol[a]];
                nxt[6*a+1] = f.x; nxt[6*a+2] = f.y; nxt[6*a+3] = f.z; nxt[6*a+4] = f.w;
                nxt[6*a+5] = xb[orr[a]];
            }
        }

        float a0 = 0.f, a1 = 0.f, a2 = 0.f, a3 = 0.f;
        #pragma unroll
        for (int a = 0; a < 3; ++a)
            #pragma unroll
            for (int d = 0; d < 3; ++d) {
                a0 += cur[6*a + 0 + d] * K[0][3*a+d];
                a1 += cur[6*a + 1 + d] * K[1][3*a+d];
                a2 += cur[6*a + 2 + d] * K[2][3*a+d];
                a3 += cur[6*a + 3 + d] * K[3][3*a+d];
            }
        float4 o; o.x = a0; o.y = a1; o.z = a2; o.w = a3;
        *(float4*)(y + (size_t)b * HW + (size_t)((unsigned)h * W + w)) = o;
    }
}

extern "C" void kernel_launch(void* const* d_in, const int* in_sizes, int n_in,
                              void* d_out, int out_size, void* d_ws, size_t ws_size,
                              hipStream_t stream)
{
    const float* image = (const float*)d_in[0];  // (1,1024,1024)
    const float* x     = (const float*)d_in[1];  // (8,1,1024,1024)
    const float* kw    = (const float*)d_in[2];  // (9,1,3,3)
    const float* kb    = (const float*)d_in[3];  // (9,)
    float* y = (float*)d_out;                    // (8,1,1024,1024)

    dim3 grid(W / 512, H / 8);                   // (2, 128) = 256 blocks, 16 waves/CU
    smblock_kernel<<<grid, 1024, 0, stream>>>(image, x, kw, kb, y);
}